// Round 1
// baseline (3243.010 us; speedup 1.0000x reference)
//
#include <hip/hip_runtime.h>

#define N_NODES 50000
#define HDIM 64
#define E_EDGES 800000

// One wave handles 4 consecutive edges; each 16-lane group handles one edge
// row of H=64 floats as float4 (16 B/lane, fully coalesced on feat).
__global__ void __launch_bounds__(256) agg_kernel(
        const float* __restrict__ h,
        const float* __restrict__ feat,
        const int* __restrict__ src,
        const int* __restrict__ dst,
        float* __restrict__ agg) {
    const int tid    = blockIdx.x * 256 + threadIdx.x;
    const int lane   = threadIdx.x & 63;
    const int sub    = lane >> 4;      // edge index within the wave's group of 4
    const int q      = lane & 15;      // float4 slot within the 64-float row
    const int waveId = tid >> 6;
    const int e      = waveId * 4 + sub;
    if (e >= E_EDGES) return;

    const int s = src[e];
    const int d = dst[e];

    const float4 f  = *(const float4*)&feat[(size_t)e * HDIM + q * 4];
    const float4 hv = *(const float4*)&h[(size_t)s * HDIM + q * 4];

    float* p = &agg[(size_t)d * HDIM + q * 4];
    atomicAdd(p + 0, f.x * hv.x);
    atomicAdd(p + 1, f.y * hv.y);
    atomicAdd(p + 2, f.z * hv.z);
    atomicAdd(p + 3, f.w * hv.w);
}

// One wave per node. x = concat(a1[n], a2[n]) (128), W is [128][64] row-major.
// out[n][lane] = h_in[n][lane] + relu(sum_k x[k] * W[k][lane] + b[lane])
__global__ void __launch_bounds__(256) mlp_kernel(
        const float* __restrict__ h_in,
        const float* __restrict__ a1,
        const float* __restrict__ a2,
        const float* __restrict__ W,
        const float* __restrict__ b,
        float* __restrict__ h_out) {
    __shared__ float Wlds[2 * HDIM * HDIM];   // 8192 floats = 32 KB

    const int tid = threadIdx.x;
    // Cooperative load of W into LDS: 8192 floats / (256 threads * 4) = 8 iters
    for (int i = tid * 4; i < 2 * HDIM * HDIM; i += 256 * 4) {
        *(float4*)&Wlds[i] = *(const float4*)&W[i];
    }
    __syncthreads();

    const int lane = tid & 63;
    const int node = blockIdx.x * 4 + (tid >> 6);
    if (node >= N_NODES) return;

    const size_t base = (size_t)node * HDIM;
    const float x1 = a1[base + lane];
    const float x2 = a2[base + lane];

    float acc = b[lane];
#pragma unroll
    for (int k = 0; k < HDIM; ++k) {
        acc = fmaf(__shfl(x1, k), Wlds[k * HDIM + lane], acc);
    }
#pragma unroll
    for (int k = 0; k < HDIM; ++k) {
        acc = fmaf(__shfl(x2, k), Wlds[(HDIM + k) * HDIM + lane], acc);
    }

    h_out[base + lane] = h_in[base + lane] + fmaxf(acc, 0.0f);
}

extern "C" void kernel_launch(void* const* d_in, const int* in_sizes, int n_in,
                              void* d_out, int out_size, void* d_ws, size_t ws_size,
                              hipStream_t stream) {
    const float* h     = (const float*)d_in[0];
    const float* feat1 = (const float*)d_in[1];
    const float* feat2 = (const float*)d_in[2];
    const float* W1    = (const float*)d_in[3];
    const float* b1    = (const float*)d_in[4];
    const float* W2    = (const float*)d_in[5];
    const float* b2    = (const float*)d_in[6];
    const int*   src1  = (const int*)d_in[7];
    const int*   dst1  = (const int*)d_in[8];
    const int*   src2  = (const int*)d_in[9];
    const int*   dst2  = (const int*)d_in[10];

    float* out = (float*)d_out;
    float* a1  = (float*)d_ws;
    float* a2  = a1 + (size_t)N_NODES * HDIM;

    const size_t aggBytes = 2 * (size_t)N_NODES * HDIM * sizeof(float);

    // Edge-parallel agg: 4 edges per wave, 4 waves per block -> 16 edges/block
    const int aggBlocks = (E_EDGES + 15) / 16;
    const int mlpBlocks = (N_NODES + 3) / 4;

    // ---- Layer 1 ----
    hipMemsetAsync(d_ws, 0, aggBytes, stream);
    agg_kernel<<<aggBlocks, 256, 0, stream>>>(h, feat1, src1, dst1, a1);
    agg_kernel<<<aggBlocks, 256, 0, stream>>>(h, feat2, src2, dst2, a2);
    mlp_kernel<<<mlpBlocks, 256, 0, stream>>>(h, a1, a2, W1, b1, out);

    // ---- Layer 2 (aggregates from updated h in d_out; in-place residual) ----
    hipMemsetAsync(d_ws, 0, aggBytes, stream);
    agg_kernel<<<aggBlocks, 256, 0, stream>>>(out, feat1, src1, dst1, a1);
    agg_kernel<<<aggBlocks, 256, 0, stream>>>(out, feat2, src2, dst2, a2);
    mlp_kernel<<<mlpBlocks, 256, 0, stream>>>(out, a1, a2, W2, b2, out);
}

// Round 2
// 1206.967 us; speedup vs baseline: 2.6869x; 2.6869x over previous
//
#include <hip/hip_runtime.h>

#define N_NODES 50000
#define HDIM 64
#define E_EDGES 800000
#define SCAN_T 1024

// ---------------- CSR build: histogram -> scan -> scatter ----------------

__global__ void __launch_bounds__(256) hist_kernel(
        const int* __restrict__ dst, int* __restrict__ cnt) {
    int e = blockIdx.x * 256 + threadIdx.x;
    if (e < E_EDGES) atomicAdd(&cnt[dst[e]], 1);
}

// Single-block exclusive scan of cnt[0..N) -> off[0..N], plus cursor copy.
__global__ void __launch_bounds__(SCAN_T) scan_kernel(
        const int* __restrict__ cnt, int* __restrict__ off, int* __restrict__ cur) {
    __shared__ int lds[SCAN_T];
    const int t = threadIdx.x;
    const int chunk = (N_NODES + SCAN_T - 1) / SCAN_T;   // 49
    const int beg = t * chunk;
    const int end = min(beg + chunk, N_NODES);

    int sum = 0;
    for (int i = beg; i < end; ++i) sum += cnt[i];
    lds[t] = sum;
    __syncthreads();

    // inclusive Hillis-Steele over 1024 partials
    for (int s = 1; s < SCAN_T; s <<= 1) {
        int v = (t >= s) ? lds[t - s] : 0;
        __syncthreads();
        lds[t] += v;
        __syncthreads();
    }

    int run = lds[t] - sum;   // exclusive prefix for this thread's chunk
    for (int i = beg; i < end; ++i) {
        off[i] = run;
        cur[i] = run;
        run += cnt[i];
    }
    if (t == SCAN_T - 1) off[N_NODES] = lds[SCAN_T - 1];
}

__global__ void __launch_bounds__(256) scatter_kernel(
        const int* __restrict__ src, const int* __restrict__ dst,
        int* __restrict__ cur, int2* __restrict__ pairs) {
    int e = blockIdx.x * 256 + threadIdx.x;
    if (e >= E_EDGES) return;
    int pos = atomicAdd(&cur[dst[e]], 1);
    pairs[pos] = make_int2(src[e], e);
}

// ---------------- CSR aggregation: one wave per node, no fp atomics ------

__global__ void __launch_bounds__(256) agg_csr_kernel(
        const float* __restrict__ h,
        const float* __restrict__ feat,
        const int* __restrict__ off,
        const int2* __restrict__ pairs,
        float* __restrict__ agg) {
    const int lane = threadIdx.x & 63;
    const int node = blockIdx.x * 4 + (threadIdx.x >> 6);
    if (node >= N_NODES) return;

    const int beg = off[node];
    const int end = off[node + 1];

    float acc = 0.0f;
    int i = beg;
    if (i < end) {
        int2 p = pairs[i];
        for (; i + 1 < end; ++i) {
            int2 pn = pairs[i + 1];                       // prefetch next pair
            acc = fmaf(feat[(size_t)p.y * HDIM + lane],
                       h[(size_t)p.x * HDIM + lane], acc);
            p = pn;
        }
        acc = fmaf(feat[(size_t)p.y * HDIM + lane],
                   h[(size_t)p.x * HDIM + lane], acc);
    }
    agg[(size_t)node * HDIM + lane] = acc;
}

// ---------------- fused linear + relu + residual -------------------------

__global__ void __launch_bounds__(256) mlp_kernel(
        const float* __restrict__ h_in,
        const float* __restrict__ a1,
        const float* __restrict__ a2,
        const float* __restrict__ W,
        const float* __restrict__ b,
        float* __restrict__ h_out) {
    __shared__ float Wlds[2 * HDIM * HDIM];   // 32 KB

    const int tid = threadIdx.x;
    for (int i = tid * 4; i < 2 * HDIM * HDIM; i += 256 * 4) {
        *(float4*)&Wlds[i] = *(const float4*)&W[i];
    }
    __syncthreads();

    const int lane = tid & 63;
    const int stride = gridDim.x * 4;
    for (int node = blockIdx.x * 4 + (tid >> 6); node < N_NODES; node += stride) {
        const size_t base = (size_t)node * HDIM;
        const float x1 = a1[base + lane];
        const float x2 = a2[base + lane];

        float acc = b[lane];
#pragma unroll
        for (int k = 0; k < HDIM; ++k)
            acc = fmaf(__shfl(x1, k), Wlds[k * HDIM + lane], acc);
#pragma unroll
        for (int k = 0; k < HDIM; ++k)
            acc = fmaf(__shfl(x2, k), Wlds[(HDIM + k) * HDIM + lane], acc);

        h_out[base + lane] = h_in[base + lane] + fmaxf(acc, 0.0f);
    }
}

// ---------------- fallback (round-1 atomic path) -------------------------

__global__ void __launch_bounds__(256) agg_atomic_kernel(
        const float* __restrict__ h,
        const float* __restrict__ feat,
        const int* __restrict__ src,
        const int* __restrict__ dst,
        float* __restrict__ agg) {
    const int tid  = blockIdx.x * 256 + threadIdx.x;
    const int lane = threadIdx.x & 63;
    const int sub  = lane >> 4;
    const int q    = lane & 15;
    const int e    = (tid >> 6) * 4 + sub;
    if (e >= E_EDGES) return;
    const int s = src[e];
    const int d = dst[e];
    const float4 f  = *(const float4*)&feat[(size_t)e * HDIM + q * 4];
    const float4 hv = *(const float4*)&h[(size_t)s * HDIM + q * 4];
    float* p = &agg[(size_t)d * HDIM + q * 4];
    atomicAdd(p + 0, f.x * hv.x);
    atomicAdd(p + 1, f.y * hv.y);
    atomicAdd(p + 2, f.z * hv.z);
    atomicAdd(p + 3, f.w * hv.w);
}

extern "C" void kernel_launch(void* const* d_in, const int* in_sizes, int n_in,
                              void* d_out, int out_size, void* d_ws, size_t ws_size,
                              hipStream_t stream) {
    const float* h     = (const float*)d_in[0];
    const float* feat1 = (const float*)d_in[1];
    const float* feat2 = (const float*)d_in[2];
    const float* W1    = (const float*)d_in[3];
    const float* b1    = (const float*)d_in[4];
    const float* W2    = (const float*)d_in[5];
    const float* b2    = (const float*)d_in[6];
    const int*   src1  = (const int*)d_in[7];
    const int*   dst1  = (const int*)d_in[8];
    const int*   src2  = (const int*)d_in[9];
    const int*   dst2  = (const int*)d_in[10];

    float* out = (float*)d_out;

    // workspace layout
    float* a1   = (float*)d_ws;                   // N*H
    float* a2   = a1 + (size_t)N_NODES * HDIM;    // N*H
    int*   cnt1 = (int*)(a2 + (size_t)N_NODES * HDIM);
    int*   cnt2 = cnt1 + N_NODES;
    int*   off1 = cnt2 + N_NODES;
    int*   off2 = off1 + (N_NODES + 1);
    int*   cur1 = off2 + (N_NODES + 1);
    int*   cur2 = cur1 + N_NODES;
    int2*  pairs1 = (int2*)(cur2 + N_NODES);
    int2*  pairs2 = pairs1 + E_EDGES;

    const size_t needed = (char*)(pairs2 + E_EDGES) - (char*)d_ws;

    const int eBlocks   = (E_EDGES + 255) / 256;
    const int aggBlocks = (N_NODES + 3) / 4;

    if (ws_size >= needed) {
        // ---- build CSR once, reuse for both layers ----
        hipMemsetAsync(cnt1, 0, 2 * (size_t)N_NODES * sizeof(int), stream);
        hist_kernel<<<eBlocks, 256, 0, stream>>>(dst1, cnt1);
        hist_kernel<<<eBlocks, 256, 0, stream>>>(dst2, cnt2);
        scan_kernel<<<1, SCAN_T, 0, stream>>>(cnt1, off1, cur1);
        scan_kernel<<<1, SCAN_T, 0, stream>>>(cnt2, off2, cur2);
        scatter_kernel<<<eBlocks, 256, 0, stream>>>(src1, dst1, cur1, pairs1);
        scatter_kernel<<<eBlocks, 256, 0, stream>>>(src2, dst2, cur2, pairs2);

        // ---- layer 1 ----
        agg_csr_kernel<<<aggBlocks, 256, 0, stream>>>(h, feat1, off1, pairs1, a1);
        agg_csr_kernel<<<aggBlocks, 256, 0, stream>>>(h, feat2, off2, pairs2, a2);
        mlp_kernel<<<1024, 256, 0, stream>>>(h, a1, a2, W1, b1, out);

        // ---- layer 2 ----
        agg_csr_kernel<<<aggBlocks, 256, 0, stream>>>(out, feat1, off1, pairs1, a1);
        agg_csr_kernel<<<aggBlocks, 256, 0, stream>>>(out, feat2, off2, pairs2, a2);
        mlp_kernel<<<1024, 256, 0, stream>>>(out, a1, a2, W2, b2, out);
    } else {
        // ---- fallback: atomic scatter path ----
        const size_t aggBytes = 2 * (size_t)N_NODES * HDIM * sizeof(float);
        const int atomBlocks = (E_EDGES + 15) / 16;

        hipMemsetAsync(d_ws, 0, aggBytes, stream);
        agg_atomic_kernel<<<atomBlocks, 256, 0, stream>>>(h, feat1, src1, dst1, a1);
        agg_atomic_kernel<<<atomBlocks, 256, 0, stream>>>(h, feat2, src2, dst2, a2);
        mlp_kernel<<<1024, 256, 0, stream>>>(h, a1, a2, W1, b1, out);

        hipMemsetAsync(d_ws, 0, aggBytes, stream);
        agg_atomic_kernel<<<atomBlocks, 256, 0, stream>>>(out, feat1, src1, dst1, a1);
        agg_atomic_kernel<<<atomBlocks, 256, 0, stream>>>(out, feat2, src2, dst2, a2);
        mlp_kernel<<<1024, 256, 0, stream>>>(out, a1, a2, W2, b2, out);
    }
}

// Round 3
// 1014.167 us; speedup vs baseline: 3.1977x; 1.1901x over previous
//
#include <hip/hip_runtime.h>

#define N_NODES 50000
#define HDIM 64
#define E_EDGES 800000
#define SCAN_T 1024

// ---------------- CSR build: histogram -> scan -> scatter ----------------
// All build kernels handle BOTH relations in one launch (blockIdx.y / .x).

__global__ void __launch_bounds__(256) hist_kernel(
        const int* __restrict__ dst1, const int* __restrict__ dst2,
        int* __restrict__ cnt1, int* __restrict__ cnt2) {
    const int* dst = blockIdx.y ? dst2 : dst1;
    int* cnt       = blockIdx.y ? cnt2 : cnt1;
    int e = blockIdx.x * 256 + threadIdx.x;
    if (e < E_EDGES) atomicAdd(&cnt[dst[e]], 1);
}

// Two blocks: block b scans relation b's cnt -> off (+cursor copy).
__global__ void __launch_bounds__(SCAN_T) scan_kernel(
        const int* __restrict__ cnt1, const int* __restrict__ cnt2,
        int* __restrict__ off1, int* __restrict__ off2,
        int* __restrict__ cur1, int* __restrict__ cur2) {
    const int* cnt = blockIdx.x ? cnt2 : cnt1;
    int* off       = blockIdx.x ? off2 : off1;
    int* cur       = blockIdx.x ? cur2 : cur1;

    __shared__ int lds[SCAN_T];
    const int t = threadIdx.x;
    const int chunk = (N_NODES + SCAN_T - 1) / SCAN_T;   // 49
    const int beg = t * chunk;
    const int end = min(beg + chunk, N_NODES);

    int sum = 0;
    for (int i = beg; i < end; ++i) sum += cnt[i];
    lds[t] = sum;
    __syncthreads();

    for (int s = 1; s < SCAN_T; s <<= 1) {
        int v = (t >= s) ? lds[t - s] : 0;
        __syncthreads();
        lds[t] += v;
        __syncthreads();
    }

    int run = lds[t] - sum;
    for (int i = beg; i < end; ++i) {
        off[i] = run;
        cur[i] = run;
        run += cnt[i];
    }
    if (t == SCAN_T - 1) off[N_NODES] = lds[SCAN_T - 1];
}

__global__ void __launch_bounds__(256) scatter_kernel(
        const int* __restrict__ src1, const int* __restrict__ dst1,
        const int* __restrict__ src2, const int* __restrict__ dst2,
        int* __restrict__ cur1, int* __restrict__ cur2,
        int2* __restrict__ pairs1, int2* __restrict__ pairs2) {
    const int* src = blockIdx.y ? src2 : src1;
    const int* dst = blockIdx.y ? dst2 : dst1;
    int* cur       = blockIdx.y ? cur2 : cur1;
    int2* pairs    = blockIdx.y ? pairs2 : pairs1;
    int e = blockIdx.x * 256 + threadIdx.x;
    if (e >= E_EDGES) return;
    int pos = atomicAdd(&cur[dst[e]], 1);
    pairs[pos] = make_int2(src[e], e);
}

// ---------------- CSR aggregation: one wave per node, 4 edges/iter -------
// Wave = 4 groups of 16 lanes; group g handles edges beg+g, beg+g+4, ...
// Each group covers the full 64-float row as float4/lane. Cross-group
// reduction via shfl_xor(16), shfl_xor(32); one 16-lane float4 row write.

__global__ void __launch_bounds__(256) agg_csr_kernel(
        const float* __restrict__ h,
        const float* __restrict__ feat1, const float* __restrict__ feat2,
        const int* __restrict__ off1, const int* __restrict__ off2,
        const int2* __restrict__ pairs1, const int2* __restrict__ pairs2,
        float* __restrict__ a1, float* __restrict__ a2) {
    const float* feat  = blockIdx.y ? feat2  : feat1;
    const int* off     = blockIdx.y ? off2   : off1;
    const int2* pairs  = blockIdx.y ? pairs2 : pairs1;
    float* agg         = blockIdx.y ? a2     : a1;

    const int tid  = threadIdx.x;
    const int lane = tid & 63;
    const int g    = lane >> 4;     // edge group 0..3
    const int q    = lane & 15;     // float4 column slot
    const int node = blockIdx.x * 4 + (tid >> 6);
    if (node >= N_NODES) return;

    const int beg = off[node];
    const int end = off[node + 1];

    float4 acc = make_float4(0.f, 0.f, 0.f, 0.f);
    int i = beg + g;
    if (i < end) {
        int2 p = pairs[i];
        for (; i + 4 < end; i += 4) {
            int2 pn = pairs[i + 4];                      // prefetch next pair
            const float4 f  = *(const float4*)&feat[(size_t)p.y * HDIM + q * 4];
            const float4 hv = *(const float4*)&h[(size_t)p.x * HDIM + q * 4];
            acc.x = fmaf(f.x, hv.x, acc.x);
            acc.y = fmaf(f.y, hv.y, acc.y);
            acc.z = fmaf(f.z, hv.z, acc.z);
            acc.w = fmaf(f.w, hv.w, acc.w);
            p = pn;
        }
        const float4 f  = *(const float4*)&feat[(size_t)p.y * HDIM + q * 4];
        const float4 hv = *(const float4*)&h[(size_t)p.x * HDIM + q * 4];
        acc.x = fmaf(f.x, hv.x, acc.x);
        acc.y = fmaf(f.y, hv.y, acc.y);
        acc.z = fmaf(f.z, hv.z, acc.z);
        acc.w = fmaf(f.w, hv.w, acc.w);
    }

    // combine the 4 groups (lanes differing in bits 4 and 5)
    acc.x += __shfl_xor(acc.x, 16); acc.y += __shfl_xor(acc.y, 16);
    acc.z += __shfl_xor(acc.z, 16); acc.w += __shfl_xor(acc.w, 16);
    acc.x += __shfl_xor(acc.x, 32); acc.y += __shfl_xor(acc.y, 32);
    acc.z += __shfl_xor(acc.z, 32); acc.w += __shfl_xor(acc.w, 32);

    if (lane < 16) {
        *(float4*)&agg[(size_t)node * HDIM + q * 4] = acc;
    }
}

// ---------------- fused linear + relu + residual -------------------------

__global__ void __launch_bounds__(256) mlp_kernel(
        const float* __restrict__ h_in,
        const float* __restrict__ a1,
        const float* __restrict__ a2,
        const float* __restrict__ W,
        const float* __restrict__ b,
        float* __restrict__ h_out) {
    __shared__ float Wlds[2 * HDIM * HDIM];   // 32 KB

    const int tid = threadIdx.x;
    for (int i = tid * 4; i < 2 * HDIM * HDIM; i += 256 * 4) {
        *(float4*)&Wlds[i] = *(const float4*)&W[i];
    }
    __syncthreads();

    const int lane = tid & 63;
    const int stride = gridDim.x * 4;
    for (int node = blockIdx.x * 4 + (tid >> 6); node < N_NODES; node += stride) {
        const size_t base = (size_t)node * HDIM;
        const float x1 = a1[base + lane];
        const float x2 = a2[base + lane];

        float acc = b[lane];
#pragma unroll
        for (int k = 0; k < HDIM; ++k)
            acc = fmaf(__shfl(x1, k), Wlds[k * HDIM + lane], acc);
#pragma unroll
        for (int k = 0; k < HDIM; ++k)
            acc = fmaf(__shfl(x2, k), Wlds[(HDIM + k) * HDIM + lane], acc);

        h_out[base + lane] = h_in[base + lane] + fmaxf(acc, 0.0f);
    }
}

// ---------------- fallback (atomic path, if ws too small) ----------------

__global__ void __launch_bounds__(256) agg_atomic_kernel(
        const float* __restrict__ h,
        const float* __restrict__ feat,
        const int* __restrict__ src,
        const int* __restrict__ dst,
        float* __restrict__ agg) {
    const int tid  = blockIdx.x * 256 + threadIdx.x;
    const int lane = threadIdx.x & 63;
    const int sub  = lane >> 4;
    const int q    = lane & 15;
    const int e    = (tid >> 6) * 4 + sub;
    if (e >= E_EDGES) return;
    const int s = src[e];
    const int d = dst[e];
    const float4 f  = *(const float4*)&feat[(size_t)e * HDIM + q * 4];
    const float4 hv = *(const float4*)&h[(size_t)s * HDIM + q * 4];
    float* p = &agg[(size_t)d * HDIM + q * 4];
    atomicAdd(p + 0, f.x * hv.x);
    atomicAdd(p + 1, f.y * hv.y);
    atomicAdd(p + 2, f.z * hv.z);
    atomicAdd(p + 3, f.w * hv.w);
}

extern "C" void kernel_launch(void* const* d_in, const int* in_sizes, int n_in,
                              void* d_out, int out_size, void* d_ws, size_t ws_size,
                              hipStream_t stream) {
    const float* h     = (const float*)d_in[0];
    const float* feat1 = (const float*)d_in[1];
    const float* feat2 = (const float*)d_in[2];
    const float* W1    = (const float*)d_in[3];
    const float* b1    = (const float*)d_in[4];
    const float* W2    = (const float*)d_in[5];
    const float* b2    = (const float*)d_in[6];
    const int*   src1  = (const int*)d_in[7];
    const int*   dst1  = (const int*)d_in[8];
    const int*   src2  = (const int*)d_in[9];
    const int*   dst2  = (const int*)d_in[10];

    float* out = (float*)d_out;

    // workspace layout
    float* a1   = (float*)d_ws;                   // N*H
    float* a2   = a1 + (size_t)N_NODES * HDIM;    // N*H
    int*   cnt1 = (int*)(a2 + (size_t)N_NODES * HDIM);
    int*   cnt2 = cnt1 + N_NODES;
    int*   off1 = cnt2 + N_NODES;
    int*   off2 = off1 + (N_NODES + 1);
    int*   cur1 = off2 + (N_NODES + 1);
    int*   cur2 = cur1 + N_NODES;
    int2*  pairs1 = (int2*)(cur2 + N_NODES);
    int2*  pairs2 = pairs1 + E_EDGES;

    const size_t needed = (char*)(pairs2 + E_EDGES) - (char*)d_ws;

    const int eBlocks   = (E_EDGES + 255) / 256;
    const int nBlocks   = (N_NODES + 3) / 4;

    if (ws_size >= needed) {
        // ---- build CSR once (both relations per launch) ----
        hipMemsetAsync(cnt1, 0, 2 * (size_t)N_NODES * sizeof(int), stream);
        hist_kernel<<<dim3(eBlocks, 2), 256, 0, stream>>>(dst1, dst2, cnt1, cnt2);
        scan_kernel<<<2, SCAN_T, 0, stream>>>(cnt1, cnt2, off1, off2, cur1, cur2);
        scatter_kernel<<<dim3(eBlocks, 2), 256, 0, stream>>>(
            src1, dst1, src2, dst2, cur1, cur2, pairs1, pairs2);

        // ---- layer 1 ----
        agg_csr_kernel<<<dim3(nBlocks, 2), 256, 0, stream>>>(
            h, feat1, feat2, off1, off2, pairs1, pairs2, a1, a2);
        mlp_kernel<<<1024, 256, 0, stream>>>(h, a1, a2, W1, b1, out);

        // ---- layer 2 ----
        agg_csr_kernel<<<dim3(nBlocks, 2), 256, 0, stream>>>(
            out, feat1, feat2, off1, off2, pairs1, pairs2, a1, a2);
        mlp_kernel<<<1024, 256, 0, stream>>>(out, a1, a2, W2, b2, out);
    } else {
        // ---- fallback: atomic scatter path ----
        const size_t aggBytes = 2 * (size_t)N_NODES * HDIM * sizeof(float);
        const int atomBlocks = (E_EDGES + 15) / 16;

        hipMemsetAsync(d_ws, 0, aggBytes, stream);
        agg_atomic_kernel<<<atomBlocks, 256, 0, stream>>>(h, feat1, src1, dst1, a1);
        agg_atomic_kernel<<<atomBlocks, 256, 0, stream>>>(h, feat2, src2, dst2, a2);
        mlp_kernel<<<1024, 256, 0, stream>>>(h, a1, a2, W1, b1, out);

        hipMemsetAsync(d_ws, 0, aggBytes, stream);
        agg_atomic_kernel<<<atomBlocks, 256, 0, stream>>>(out, feat1, src1, dst1, a1);
        agg_atomic_kernel<<<atomBlocks, 256, 0, stream>>>(out, feat2, src2, dst2, a2);
        mlp_kernel<<<1024, 256, 0, stream>>>(out, a1, a2, W2, b2, out);
    }
}